// Round 2
// baseline (525.878 us; speedup 1.0000x reference)
//
#include <hip/hip_runtime.h>
#include <hip/hip_bf16.h>
#include <stdint.h>

typedef __hip_bfloat16 bf16;
typedef __bf16 bf16x8 __attribute__((ext_vector_type(8)));
typedef float f32x4 __attribute__((ext_vector_type(4)));

#define S_LEN 2048
#define EMB   2048
#define NH    16
#define HD    128

// async global->LDS, 16B per lane. LDS dest must be wave-uniform base + lane*16.
__device__ __forceinline__ void glds16(const void* g, void* l) {
  __builtin_amdgcn_global_load_lds(
      (__attribute__((address_space(1))) void*)g,
      (__attribute__((address_space(3))) void*)l,
      16, 0, 0);
}

// ---------------------------------------------------------------------------
// Kernel 0: f32 -> bf16 conversion (4 elements/thread, vectorized)
// ---------------------------------------------------------------------------
__global__ __launch_bounds__(256) void cvt_f32_bf16_k(
    const float* __restrict__ in, bf16* __restrict__ outp)
{
  const int i = blockIdx.x * 256 + threadIdx.x;
  const float4 v = ((const float4*)in)[i];
  bf16 tmp[4];
  tmp[0] = __float2bfloat16(v.x);
  tmp[1] = __float2bfloat16(v.y);
  tmp[2] = __float2bfloat16(v.z);
  tmp[3] = __float2bfloat16(v.w);
  ((uint2*)outp)[i] = *(const uint2*)tmp;
}

// ===========================================================================
// Phased GEMM geometry (shared by both GEMMs):
//   tile 128(M) x 256(N), BK=64, 512 threads = 8 waves (2 M x 4 N),
//   per-wave output 64x64 (4x4 fragments of 16x16), acc = 64 VGPR.
//   LDS 96KB: A dbuf 2x[128][64], B dbuf 2x[256][64], rows 128B,
//   T2 XOR-swizzle byte ^= ((row&7)<<4)  (inverse-swizzled global source,
//   linear global_load_lds dest, swizzled ds_read_b128 -> 2 lanes/bank).
//   Schedule per K-tile kt (T3/T4/T5):
//     P1: stage A(kt+1) [2 glds]; s_waitcnt vmcnt(2); s_barrier;
//         ds_read af[4][2] + bf[0..1][2]; setprio1; 16 MFMA (ni 0,1); setprio0;
//         s_barrier
//     P2: stage B(kt+1) [4 glds]; ds_read bf[2..3][2];
//         setprio1; 16 MFMA (ni 2,3); setprio0; s_barrier
//   vmcnt(2) leaves only the just-issued A(kt+1) in flight => A(kt),B(kt)
//   landed for every wave before any wave's ds_read (vmcnt is per-wave; the
//   barrier after it makes the guarantee collective). Buffer re-stage always
//   issues after a barrier that follows the last read of its old contents.
// ===========================================================================

// ---------------------------------------------------------------------------
// Kernel 1: qkv = x @ w_qkv^T + b_qkv. Q,K scattered into [b,h,s,d];
// V written TRANSPOSED into v_t [b,h,d,s]. Grid 768 = 3/CU balanced.
// ---------------------------------------------------------------------------
__global__ __launch_bounds__(512, 2) void gemm_qkv_k(
    const bf16* __restrict__ x, const bf16* __restrict__ wq,
    const float* __restrict__ bias,
    bf16* __restrict__ q_ws, bf16* __restrict__ k_ws, bf16* __restrict__ v_t)
{
  __shared__ alignas(16) bf16 sA[2][128 * 64];
  __shared__ alignas(16) bf16 sB[2][256 * 64];

  const int t    = threadIdx.x;
  const int lane = t & 63, quad = lane >> 4, l15 = lane & 15;
  const int w    = t >> 6, wm = w >> 2, wn = w & 3;

  // XCD-aware bijective swizzle: 768 blocks, 96/XCD -> 32 mb x 3 nb per XCD
  const int bid = blockIdx.x;
  const int swz = (bid & 7) * 96 + (bid >> 3);
  const int m0  = (swz & 31) * 128;
  const int n0  = (swz >> 5) * 256;

  auto stA = [&](int k0, int buf) {
#pragma unroll
    for (int i = 0; i < 2; ++i) {
      const int lin = i * 512 + t;                    // 0..1023
      const int row = lin >> 3;                       // 0..127
      const int cb  = ((lin & 7) * 16) ^ ((row & 7) << 4);   // byte col, [0,128)
      glds16(x + (size_t)(m0 + row) * EMB + k0 + (cb >> 1),
             sA[buf] + (size_t)lin * 8);
    }
  };
  auto stB = [&](int k0, int buf) {
#pragma unroll
    for (int i = 0; i < 4; ++i) {
      const int lin = i * 512 + t;                    // 0..2047
      const int row = lin >> 3;                       // 0..255
      const int cb  = ((lin & 7) * 16) ^ ((row & 7) << 4);
      glds16(wq + (size_t)(n0 + row) * EMB + k0 + (cb >> 1),
             sB[buf] + (size_t)lin * 8);
    }
  };

  f32x4 acc[4][4];
#pragma unroll
  for (int mi = 0; mi < 4; ++mi)
#pragma unroll
    for (int ni = 0; ni < 4; ++ni)
#pragma unroll
      for (int r = 0; r < 4; ++r) acc[mi][ni][r] = 0.f;

  stA(0, 0);
  stB(0, 0);

  for (int kt = 0; kt < 32; ++kt) {
    const int cur = kt & 1, nxt = cur ^ 1;
    // ---- phase 1 ----
    if (kt + 1 < 32) {
      stA((kt + 1) * 64, nxt);
      asm volatile("s_waitcnt vmcnt(2)" ::: "memory");
    } else {
      asm volatile("s_waitcnt vmcnt(0)" ::: "memory");
    }
    __builtin_amdgcn_s_barrier();

    bf16x8 af[4][2], bfr[4][2];
#pragma unroll
    for (int mi = 0; mi < 4; ++mi)
#pragma unroll
      for (int kk = 0; kk < 2; ++kk) {
        const int ar = wm * 64 + mi * 16 + l15;
        const int c  = (kk * 64 + quad * 16) ^ ((ar & 7) << 4);
        af[mi][kk] = *(const bf16x8*)(sA[cur] + ar * 64 + (c >> 1));
      }
#pragma unroll
    for (int ni = 0; ni < 2; ++ni)
#pragma unroll
      for (int kk = 0; kk < 2; ++kk) {
        const int br = wn * 64 + ni * 16 + l15;
        const int c  = (kk * 64 + quad * 16) ^ ((br & 7) << 4);
        bfr[ni][kk] = *(const bf16x8*)(sB[cur] + br * 64 + (c >> 1));
      }
    __builtin_amdgcn_s_setprio(1);
#pragma unroll
    for (int mi = 0; mi < 4; ++mi)
#pragma unroll
      for (int ni = 0; ni < 2; ++ni)
#pragma unroll
        for (int kk = 0; kk < 2; ++kk)
          acc[mi][ni] = __builtin_amdgcn_mfma_f32_16x16x32_bf16(af[mi][kk], bfr[ni][kk], acc[mi][ni], 0, 0, 0);
    __builtin_amdgcn_s_setprio(0);
    __builtin_amdgcn_s_barrier();

    // ---- phase 2 ----
    if (kt + 1 < 32) stB((kt + 1) * 64, nxt);
#pragma unroll
    for (int ni = 2; ni < 4; ++ni)
#pragma unroll
      for (int kk = 0; kk < 2; ++kk) {
        const int br = wn * 64 + ni * 16 + l15;
        const int c  = (kk * 64 + quad * 16) ^ ((br & 7) << 4);
        bfr[ni][kk] = *(const bf16x8*)(sB[cur] + br * 64 + (c >> 1));
      }
    __builtin_amdgcn_s_setprio(1);
#pragma unroll
    for (int mi = 0; mi < 4; ++mi)
#pragma unroll
      for (int ni = 2; ni < 4; ++ni)
#pragma unroll
        for (int kk = 0; kk < 2; ++kk)
          acc[mi][ni] = __builtin_amdgcn_mfma_f32_16x16x32_bf16(af[mi][kk], bfr[ni][kk], acc[mi][ni], 0, 0, 0);
    __builtin_amdgcn_s_setprio(0);
    __builtin_amdgcn_s_barrier();
  }

  // ---- epilogue: bias + scatter (Q/K [b,h,s,d]; V transposed [b,h,d,s]) ----
  const int which = n0 >> 11;                 // 0=q,1=k,2=v (block-uniform)
  bf16* dst = (which == 0) ? q_ws : ((which == 1) ? k_ws : v_t);

#pragma unroll
  for (int mi = 0; mi < 4; ++mi) {
#pragma unroll
    for (int ni = 0; ni < 4; ++ni) {
      const int n_g = n0 + wn * 64 + ni * 16 + l15;
      const int h   = (n_g >> 7) & 15;
      const int d   = n_g & 127;
      const float bv = bias[n_g];
#pragma unroll
      for (int r = 0; r < 4; ++r) {
        const int m_g = m0 + wm * 64 + mi * 16 + quad * 4 + r;
        const int b   = m_g >> 11;
        const int s   = m_g & 2047;
        const size_t idx = (which == 2)
            ? ((size_t)(b * NH + h) * HD + d) * S_LEN + s      // V: [b,h,d,s]
            : ((size_t)(b * NH + h) * S_LEN + s) * HD + d;     // Q/K: [b,h,s,d]
        dst[idx] = __float2bfloat16(acc[mi][ni][r] + bv);
      }
    }
  }
}

// ---------------------------------------------------------------------------
// Kernel 2: causal flash attention (unchanged from round 1 — passed).
// ---------------------------------------------------------------------------
__global__ __launch_bounds__(256, 1) void attn_k(
    const bf16* __restrict__ q_ws, const bf16* __restrict__ k_ws,
    const bf16* __restrict__ v_t, bf16* __restrict__ attn_out)
{
  __shared__ alignas(16) bf16 smK[2][8192];
  __shared__ alignas(16) bf16 smV[2][8192];
  __shared__ alignas(16) bf16 smP[4][32 * 72];

  const int t    = threadIdx.x;
  const int lane = t & 63, quad = lane >> 4, l15 = lane & 15;
  const int w    = t >> 6;
  const int bh   = blockIdx.x >> 3;
  const int pr   = blockIdx.x & 7;
  const size_t hb = (size_t)bh * (S_LEN * HD);
  const int col8 = (t & 3) * 8;
  bf16* myP = smP[w];
  const float C = 0.12751745f;   // (1/sqrt(128)) * log2(e)

  auto stageK = [&](int kv0, bf16* dst) {
#pragma unroll
    for (int i = 0; i < 4; i++) {
      const int lin = i * 256 + t;
      const int c   = lin >> 8;
      const int row = (lin >> 2) & 63;
      glds16(k_ws + hb + (size_t)(kv0 + row) * HD + c * 32 + col8, dst + (size_t)lin * 8);
    }
  };
  auto stageV = [&](int kv0, bf16* dst) {
#pragma unroll
    for (int i = 0; i < 4; i++) {
      const int lin = i * 256 + t;
      const int c   = lin >> 9;
      const int row = (lin >> 2) & 127;
      glds16(v_t + hb + (size_t)row * S_LEN + kv0 + c * 32 + col8, dst + (size_t)lin * 8);
    }
  };

  for (int ph = 0; ph < 2; ++ph) {
    const int qt     = ph ? pr : (15 - pr);
    const int qbase  = qt * 128;
    const int ntiles = 2 * qt + 2;
    const int wrow0  = qbase + w * 32;
    const int wrow_hi = wrow0 + 31;

    bf16x8 qf[2][4];
#pragma unroll
    for (int mi = 0; mi < 2; ++mi)
#pragma unroll
      for (int ks = 0; ks < 4; ++ks)
        qf[mi][ks] = *(const bf16x8*)(q_ws + hb + (size_t)(wrow0 + mi * 16 + l15) * HD + ks * 32 + quad * 8);

    f32x4 o_acc[2][8];
    float m_st[2][4], l_st[2][4];
#pragma unroll
    for (int mi = 0; mi < 2; ++mi) {
#pragma unroll
      for (int dt = 0; dt < 8; ++dt)
#pragma unroll
        for (int r = 0; r < 4; ++r) o_acc[mi][dt][r] = 0.f;
#pragma unroll
      for (int r = 0; r < 4; ++r) { m_st[mi][r] = -1e30f; l_st[mi][r] = 0.f; }
    }

    stageK(0, smK[0]);
    stageV(0, smV[0]);

    for (int tile = 0; tile < ntiles; ++tile) {
      const int cur = tile & 1;
      if (tile + 1 < ntiles) {
        const int kv1 = (tile + 1) * 64;
        stageK(kv1, smK[cur ^ 1]);
        stageV(kv1, smV[cur ^ 1]);
        asm volatile("s_waitcnt vmcnt(8)" ::: "memory");
      } else {
        asm volatile("s_waitcnt vmcnt(0)" ::: "memory");
      }
      __builtin_amdgcn_s_barrier();

      const int kv0 = tile * 64;
      if (kv0 <= wrow_hi) {
        f32x4 sc[2][4];
#pragma unroll
        for (int mi = 0; mi < 2; mi++)
#pragma unroll
          for (int ni = 0; ni < 4; ni++)
#pragma unroll
            for (int r = 0; r < 4; r++) sc[mi][ni][r] = 0.f;
        const bf16* kb = smK[cur];
#pragma unroll
        for (int ks = 0; ks < 4; ++ks) {
          bf16x8 kf[4];
#pragma unroll
          for (int ni = 0; ni < 4; ++ni)
            kf[ni] = *(const bf16x8*)(kb + (ks * 64 + ni * 16 + l15) * 32 + quad * 8);
#pragma unroll
          for (int mi = 0; mi < 2; ++mi)
#pragma unroll
            for (int ni = 0; ni < 4; ++ni)
              sc[mi][ni] = __builtin_amdgcn_mfma_f32_16x16x32_bf16(qf[mi][ks], kf[ni], sc[mi][ni], 0, 0, 0);
        }

#pragma unroll
        for (int mi = 0; mi < 2; ++mi) {
          const int mrow0 = wrow0 + mi * 16;
          const bool needmask = (kv0 + 63 > mrow0);
#pragma unroll
          for (int r = 0; r < 4; ++r) {
            const int qg = mrow0 + quad * 4 + r;
            float xs[4];
            float vmax = -1e30f;
            if (needmask) {
#pragma unroll
              for (int ni = 0; ni < 4; ++ni) {
                const int kg = kv0 + ni * 16 + l15;
                float xv = sc[mi][ni][r] * C;
                xv = (kg > qg) ? -1e30f : xv;
                xs[ni] = xv;
                vmax = fmaxf(vmax, xv);
              }
            } else {
#pragma unroll
              for (int ni = 0; ni < 4; ++ni) {
                const float xv = sc[mi][ni][r] * C;
                xs[ni] = xv;
                vmax = fmaxf(vmax, xv);
              }
            }
            float m_old = m_st[mi][r];
            if (!__all(vmax <= m_old + 8.f)) {
#pragma unroll
              for (int off = 1; off < 16; off <<= 1)
                vmax = fmaxf(vmax, __shfl_xor(vmax, off, 64));
              const float mnew  = fmaxf(m_old, vmax);
              const float alpha = __builtin_amdgcn_exp2f(m_old - mnew);
              l_st[mi][r] *= alpha;
#pragma unroll
              for (int dt = 0; dt < 8; ++dt) o_acc[mi][dt][r] *= alpha;
              m_st[mi][r] = mnew;
              m_old = mnew;
            }
            float ps = 0.f;
#pragma unroll
            for (int ni = 0; ni < 4; ++ni) {
              const float p = __builtin_amdgcn_exp2f(xs[ni] - m_old);
              ps += p;
              myP[(mi * 16 + quad * 4 + r) * 72 + ni * 16 + l15] = __float2bfloat16(p);
            }
            l_st[mi][r] += ps;
          }
        }

        const bf16* vb = smV[cur];
#pragma unroll
        for (int ks2 = 0; ks2 < 2; ++ks2) {
          bf16x8 pa[2];
#pragma unroll
          for (int mi = 0; mi < 2; ++mi)
            pa[mi] = *(const bf16x8*)(myP + (mi * 16 + l15) * 72 + ks2 * 32 + quad * 8);
#pragma unroll
          for (int dt = 0; dt < 8; ++dt) {
            const bf16x8 vf = *(const bf16x8*)(vb + (ks2 * 128 + dt * 16 + l15) * 32 + quad * 8);
#pragma unroll
            for (int mi = 0; mi < 2; ++mi)
              o_acc[mi][dt] = __builtin_amdgcn_mfma_f32_16x16x32_bf16(pa[mi], vf, o_acc[mi][dt], 0, 0, 0);
          }
        }
      }
      __builtin_amdgcn_s_barrier();
    }

#pragma unroll
    for (int mi = 0; mi < 2; ++mi) {
#pragma unroll
      for (int r = 0; r < 4; ++r) {
        float l = l_st[mi][r];
#pragma unroll
        for (int off = 1; off < 16; off <<= 1) l += __shfl_xor(l, off, 64);
        const float rl = 1.f / l;
        const int sg = qbase + w * 32 + mi * 16 + quad * 4 + r;
        const size_t rowoff = hb + (size_t)sg * HD;
#pragma unroll
        for (int dt = 0; dt < 8; ++dt)
          attn_out[rowoff + dt * 16 + l15] = __float2bfloat16(o_acc[mi][dt][r] * rl);
      }
    }
  }
}

// ---------------------------------------------------------------------------
// Kernel 3: out = attn @ w_out^T + b_out, attn stored [b,h,s,d]
// (logical A[m = b*2048+s][k = h*128+d]). OUTPUT FLOAT32. Grid 256 = 1/CU.
// Same phased structure as gemm_qkv_k.
// ---------------------------------------------------------------------------
__global__ __launch_bounds__(512, 2) void gemm_out_k(
    const bf16* __restrict__ attn, const bf16* __restrict__ wo,
    const float* __restrict__ bias, float* __restrict__ out)
{
  __shared__ alignas(16) bf16 sA[2][128 * 64];
  __shared__ alignas(16) bf16 sB[2][256 * 64];

  const int t    = threadIdx.x;
  const int lane = t & 63, quad = lane >> 4, l15 = lane & 15;
  const int w    = t >> 6, wm = w >> 2, wn = w & 3;

  const int bid = blockIdx.x;
  const int swz = (bid & 7) * 32 + (bid >> 3);    // 256 blocks, 32/XCD
  const int m0  = (swz & 31) * 128;
  const int n0  = (swz >> 5) * 256;

  auto stA = [&](int k0, int buf) {
    const int h  = k0 >> 7;
    const int d0 = k0 & 127;
#pragma unroll
    for (int i = 0; i < 2; ++i) {
      const int lin = i * 512 + t;
      const int row = lin >> 3;
      const int cb  = ((lin & 7) * 16) ^ ((row & 7) << 4);
      const int m   = m0 + row;
      const int b   = m >> 11;
      const int s   = m & 2047;
      glds16(attn + ((size_t)(b * NH + h) * S_LEN + s) * HD + d0 + (cb >> 1),
             sA[buf] + (size_t)lin * 8);
    }
  };
  auto stB = [&](int k0, int buf) {
#pragma unroll
    for (int i = 0; i < 4; ++i) {
      const int lin = i * 512 + t;
      const int row = lin >> 3;
      const int cb  = ((lin & 7) * 16) ^ ((row & 7) << 4);
      glds16(wo + (size_t)(n0 + row) * EMB + k0 + (cb >> 1),
             sB[buf] + (size_t)lin * 8);
    }
  };

  f32x4 acc[4][4];
#pragma unroll
  for (int mi = 0; mi < 4; ++mi)
#pragma unroll
    for (int ni = 0; ni < 4; ++ni)
#pragma unroll
      for (int r = 0; r < 4; ++r) acc[mi][ni][r] = 0.f;

  stA(0, 0);
  stB(0, 0);

  for (int kt = 0; kt < 32; ++kt) {
    const int cur = kt & 1, nxt = cur ^ 1;
    if (kt + 1 < 32) {
      stA((kt + 1) * 64, nxt);
      asm volatile("s_waitcnt vmcnt(2)" ::: "memory");
    } else {
      asm volatile("s_waitcnt vmcnt(0)" ::: "memory");
    }
    __builtin_amdgcn_s_barrier();

    bf16x8 af[4][2], bfr[4][2];
#pragma unroll
    for (int mi = 0; mi < 4; ++mi)
#pragma unroll
      for (int kk = 0; kk < 2; ++kk) {
        const int ar = wm * 64 + mi * 16 + l15;
        const int c  = (kk * 64 + quad * 16) ^ ((ar & 7) << 4);
        af[mi][kk] = *(const bf16x8*)(sA[cur] + ar * 64 + (c >> 1));
      }
#pragma unroll
    for (int ni = 0; ni < 2; ++ni)
#pragma unroll
      for (int kk = 0; kk < 2; ++kk) {
        const int br = wn * 64 + ni * 16 + l15;
        const int c  = (kk * 64 + quad * 16) ^ ((br & 7) << 4);
        bfr[ni][kk] = *(const bf16x8*)(sB[cur] + br * 64 + (c >> 1));
      }
    __builtin_amdgcn_s_setprio(1);
#pragma unroll
    for (int mi = 0; mi < 4; ++mi)
#pragma unroll
      for (int ni = 0; ni < 2; ++ni)
#pragma unroll
        for (int kk = 0; kk < 2; ++kk)
          acc[mi][ni] = __builtin_amdgcn_mfma_f32_16x16x32_bf16(af[mi][kk], bfr[ni][kk], acc[mi][ni], 0, 0, 0);
    __builtin_amdgcn_s_setprio(0);
    __builtin_amdgcn_s_barrier();

    if (kt + 1 < 32) stB((kt + 1) * 64, nxt);
#pragma unroll
    for (int ni = 2; ni < 4; ++ni)
#pragma unroll
      for (int kk = 0; kk < 2; ++kk) {
        const int br = wn * 64 + ni * 16 + l15;
        const int c  = (kk * 64 + quad * 16) ^ ((br & 7) << 4);
        bfr[ni][kk] = *(const bf16x8*)(sB[cur] + br * 64 + (c >> 1));
      }
    __builtin_amdgcn_s_setprio(1);
#pragma unroll
    for (int mi = 0; mi < 4; ++mi)
#pragma unroll
      for (int ni = 2; ni < 4; ++ni)
#pragma unroll
        for (int kk = 0; kk < 2; ++kk)
          acc[mi][ni] = __builtin_amdgcn_mfma_f32_16x16x32_bf16(af[mi][kk], bfr[ni][kk], acc[mi][ni], 0, 0, 0);
    __builtin_amdgcn_s_setprio(0);
    __builtin_amdgcn_s_barrier();
  }

#pragma unroll
  for (int mi = 0; mi < 4; ++mi) {
#pragma unroll
    for (int ni = 0; ni < 4; ++ni) {
      const int n_g = n0 + wn * 64 + ni * 16 + l15;
      const float bv = bias[n_g];
#pragma unroll
      for (int r = 0; r < 4; ++r) {
        const int m_g = m0 + wm * 64 + mi * 16 + quad * 4 + r;
        out[(size_t)m_g * EMB + n_g] = acc[mi][ni][r] + bv;   // f32 store
      }
    }
  }
}

// ---------------------------------------------------------------------------
// Workspace layout (96 MiB):
//   [ 0,16)  MiB: xb  bf16 (x converted) -> attn output [b,h,s,d] after QKV
//   [16,40)  MiB: wqb bf16 (w_qkv converted)
//   [40,48)  MiB: wob bf16 (w_out converted)
//   [48,64)  MiB: q [b,h,s,d]
//   [64,80)  MiB: k [b,h,s,d]
//   [80,96)  MiB: v_t [b,h,d,s]
// ---------------------------------------------------------------------------
extern "C" void kernel_launch(void* const* d_in, const int* in_sizes, int n_in,
                              void* d_out, int out_size, void* d_ws, size_t ws_size,
                              hipStream_t stream)
{
  const float* x_f     = (const float*)d_in[0];
  // d_in[1] = attn_mask (causal triu) — known analytically, ignored.
  const float* w_qkv_f = (const float*)d_in[2];
  const float* b_qkv   = (const float*)d_in[3];
  const float* w_out_f = (const float*)d_in[4];
  const float* b_out   = (const float*)d_in[5];
  float* out = (float*)d_out;   // reference output dtype is float32

  char* ws = (char*)d_ws;
  const size_t MB = 1024 * 1024;
  bf16* xb   = (bf16*)(ws);
  bf16* wqb  = (bf16*)(ws + 16 * MB);
  bf16* wob  = (bf16*)(ws + 40 * MB);
  bf16* q_ws = (bf16*)(ws + 48 * MB);
  bf16* k_ws = (bf16*)(ws + 64 * MB);
  bf16* v_t  = (bf16*)(ws + 80 * MB);
  bf16* attn = xb;   // xb dead after gemm_qkv_k; distinct from q_ws (no alias)

  cvt_f32_bf16_k<<<dim3(8192), 256, 0, stream>>>(x_f, xb);
  cvt_f32_bf16_k<<<dim3(12288), 256, 0, stream>>>(w_qkv_f, wqb);
  cvt_f32_bf16_k<<<dim3(4096), 256, 0, stream>>>(w_out_f, wob);

  gemm_qkv_k<<<dim3(768), 512, 0, stream>>>(xb, wqb, b_qkv, q_ws, k_ws, v_t);
  attn_k<<<dim3(256), 256, 0, stream>>>(q_ws, k_ws, v_t, attn);
  gemm_out_k<<<dim3(256), 512, 0, stream>>>(attn, wob, b_out, out);
}

// Round 3
// 465.480 us; speedup vs baseline: 1.1298x; 1.1298x over previous
//
#include <hip/hip_runtime.h>
#include <hip/hip_bf16.h>
#include <stdint.h>

typedef __hip_bfloat16 bf16;
typedef __bf16 bf16x8 __attribute__((ext_vector_type(8)));
typedef float f32x4 __attribute__((ext_vector_type(4)));

#define S_LEN 2048
#define EMB   2048
#define NH    16
#define HD    128

// async global->LDS, 16B per lane. LDS dest must be wave-uniform base + lane*16.
__device__ __forceinline__ void glds16(const void* g, void* l) {
  __builtin_amdgcn_global_load_lds(
      (__attribute__((address_space(1))) void*)g,
      (__attribute__((address_space(3))) void*)l,
      16, 0, 0);
}

// ---------------------------------------------------------------------------
// Kernel 0: f32 -> bf16 conversion (4 elements/thread, vectorized)
// ---------------------------------------------------------------------------
__global__ __launch_bounds__(256) void cvt_f32_bf16_k(
    const float* __restrict__ in, bf16* __restrict__ outp)
{
  const int i = blockIdx.x * 256 + threadIdx.x;
  const float4 v = ((const float4*)in)[i];
  bf16 tmp[4];
  tmp[0] = __float2bfloat16(v.x);
  tmp[1] = __float2bfloat16(v.y);
  tmp[2] = __float2bfloat16(v.z);
  tmp[3] = __float2bfloat16(v.w);
  ((uint2*)outp)[i] = *(const uint2*)tmp;
}

// ===========================================================================
// Phased GEMM geometry (both GEMMs):
//   tile 128(M) x 256(N), BK=64, 512 threads = 8 waves (2 M x 4 N),
//   per-wave output 64x64 (4x4 fragments of 16x16).
//   LDS 144KB: TRIPLE buffer A[3][128][64] + B[3][256][64], rows 128B,
//   T2 XOR-swizzle byte ^= ((row&7)<<4) (inverse-swizzled global source,
//   linear global_load_lds dest, swizzled ds_read_b128 -> conflict-free).
//   Schedule per K-tile t (prefetch distance 2, ONE barrier/iter):
//     s_waitcnt vmcnt(6)   // drain tile t's 6 loads; t+1's 6 stay in flight
//     s_barrier            // all waves' tile-t data landed in LDS
//     stage(t+2 -> buf[(t+2)%3])   // issued AFTER the barrier (race-safe:
//                                  // buf[(t+2)%3]=buf[(t-1)%3], last read in
//                                  // iter t-1 which precedes barrier(t))
//     ds_read 16 frags; setprio(1); 32 MFMA; setprio(0)
//   Cover for each stage = 2 full iterations (~2x32 MFMA + ds_reads).
//   Tail: t=nt-1 uses vmcnt(0). Dispatch order kept NATURAL (n fast, m slow):
//   round-1-measured L2 locality (FETCH 90MB vs 209MB with the XCD remap).
// ===========================================================================

// ---------------------------------------------------------------------------
// Kernel 1: qkv = x @ w_qkv^T + b_qkv. Q,K scattered into [b,h,s,d];
// V written TRANSPOSED into v_t [b,h,d,s]. Grid (24,32) = 768 blocks.
// ---------------------------------------------------------------------------
__global__ __launch_bounds__(512, 1) void gemm_qkv_k(
    const bf16* __restrict__ x, const bf16* __restrict__ wq,
    const float* __restrict__ bias,
    bf16* __restrict__ q_ws, bf16* __restrict__ k_ws, bf16* __restrict__ v_t)
{
  __shared__ alignas(16) bf16 sA[3][128 * 64];
  __shared__ alignas(16) bf16 sB[3][256 * 64];

  const int t    = threadIdx.x;
  const int lane = t & 63, quad = lane >> 4, l15 = lane & 15;
  const int w    = t >> 6, wm = w >> 2, wn = w & 3;

  const int n0 = blockIdx.x * 256;
  const int m0 = blockIdx.y * 128;

  auto stA = [&](int k0, int buf) {
#pragma unroll
    for (int i = 0; i < 2; ++i) {
      const int lin = i * 512 + t;                    // 0..1023
      const int row = lin >> 3;                       // 0..127
      const int cb  = ((lin & 7) * 16) ^ ((row & 7) << 4);   // byte col [0,128)
      glds16(x + (size_t)(m0 + row) * EMB + k0 + (cb >> 1),
             sA[buf] + (size_t)lin * 8);
    }
  };
  auto stB = [&](int k0, int buf) {
#pragma unroll
    for (int i = 0; i < 4; ++i) {
      const int lin = i * 512 + t;                    // 0..2047
      const int row = lin >> 3;                       // 0..255
      const int cb  = ((lin & 7) * 16) ^ ((row & 7) << 4);
      glds16(wq + (size_t)(n0 + row) * EMB + k0 + (cb >> 1),
             sB[buf] + (size_t)lin * 8);
    }
  };

  f32x4 acc[4][4];
#pragma unroll
  for (int mi = 0; mi < 4; ++mi)
#pragma unroll
    for (int ni = 0; ni < 4; ++ni)
#pragma unroll
      for (int r = 0; r < 4; ++r) acc[mi][ni][r] = 0.f;

  stA(0, 0); stB(0, 0);
  stA(64, 1); stB(64, 1);

  int cur = 0;
  for (int kt = 0; kt < 32; ++kt) {
    if (kt < 31) asm volatile("s_waitcnt vmcnt(6)" ::: "memory");
    else         asm volatile("s_waitcnt vmcnt(0)" ::: "memory");
    __builtin_amdgcn_s_barrier();

    if (kt + 2 < 32) {
      int pf = cur - 1; if (pf < 0) pf += 3;          // (kt+2)%3
      stA((kt + 2) * 64, pf);
      stB((kt + 2) * 64, pf);
    }

    const bf16* aB = sA[cur];
    const bf16* bB = sB[cur];
    bf16x8 af[4][2], bfr[4][2];
#pragma unroll
    for (int mi = 0; mi < 4; ++mi)
#pragma unroll
      for (int kk = 0; kk < 2; ++kk) {
        const int ar = wm * 64 + mi * 16 + l15;
        const int c  = (kk * 64 + quad * 16) ^ ((ar & 7) << 4);
        af[mi][kk] = *(const bf16x8*)(aB + ar * 64 + (c >> 1));
      }
#pragma unroll
    for (int ni = 0; ni < 4; ++ni)
#pragma unroll
      for (int kk = 0; kk < 2; ++kk) {
        const int br = wn * 64 + ni * 16 + l15;
        const int c  = (kk * 64 + quad * 16) ^ ((br & 7) << 4);
        bfr[ni][kk] = *(const bf16x8*)(bB + br * 64 + (c >> 1));
      }
    __builtin_amdgcn_s_setprio(1);
#pragma unroll
    for (int mi = 0; mi < 4; ++mi)
#pragma unroll
      for (int ni = 0; ni < 4; ++ni)
#pragma unroll
        for (int kk = 0; kk < 2; ++kk)
          acc[mi][ni] = __builtin_amdgcn_mfma_f32_16x16x32_bf16(af[mi][kk], bfr[ni][kk], acc[mi][ni], 0, 0, 0);
    __builtin_amdgcn_s_setprio(0);

    cur = (cur == 2) ? 0 : cur + 1;
  }

  // ---- epilogue: bias + scatter (Q/K [b,h,s,d]; V transposed [b,h,d,s]) ----
  const int which = n0 >> 11;                 // 0=q,1=k,2=v (block-uniform)
  bf16* dst = (which == 0) ? q_ws : ((which == 1) ? k_ws : v_t);

#pragma unroll
  for (int mi = 0; mi < 4; ++mi) {
#pragma unroll
    for (int ni = 0; ni < 4; ++ni) {
      const int n_g = n0 + wn * 64 + ni * 16 + l15;
      const int h   = (n_g >> 7) & 15;
      const int d   = n_g & 127;
      const float bv = bias[n_g];
#pragma unroll
      for (int r = 0; r < 4; ++r) {
        const int m_g = m0 + wm * 64 + mi * 16 + quad * 4 + r;
        const int b   = m_g >> 11;
        const int s   = m_g & 2047;
        const size_t idx = (which == 2)
            ? ((size_t)(b * NH + h) * HD + d) * S_LEN + s      // V: [b,h,d,s]
            : ((size_t)(b * NH + h) * S_LEN + s) * HD + d;     // Q/K: [b,h,s,d]
        dst[idx] = __float2bfloat16(acc[mi][ni][r] + bv);
      }
    }
  }
}

// ---------------------------------------------------------------------------
// Kernel 2: causal flash attention (unchanged — passed rounds 1 & 2).
// ---------------------------------------------------------------------------
__global__ __launch_bounds__(256, 1) void attn_k(
    const bf16* __restrict__ q_ws, const bf16* __restrict__ k_ws,
    const bf16* __restrict__ v_t, bf16* __restrict__ attn_out)
{
  __shared__ alignas(16) bf16 smK[2][8192];
  __shared__ alignas(16) bf16 smV[2][8192];
  __shared__ alignas(16) bf16 smP[4][32 * 72];

  const int t    = threadIdx.x;
  const int lane = t & 63, quad = lane >> 4, l15 = lane & 15;
  const int w    = t >> 6;
  const int bh   = blockIdx.x >> 3;
  const int pr   = blockIdx.x & 7;
  const size_t hb = (size_t)bh * (S_LEN * HD);
  const int col8 = (t & 3) * 8;
  bf16* myP = smP[w];
  const float C = 0.12751745f;   // (1/sqrt(128)) * log2(e)

  auto stageK = [&](int kv0, bf16* dst) {
#pragma unroll
    for (int i = 0; i < 4; i++) {
      const int lin = i * 256 + t;
      const int c   = lin >> 8;
      const int row = (lin >> 2) & 63;
      glds16(k_ws + hb + (size_t)(kv0 + row) * HD + c * 32 + col8, dst + (size_t)lin * 8);
    }
  };
  auto stageV = [&](int kv0, bf16* dst) {
#pragma unroll
    for (int i = 0; i < 4; i++) {
      const int lin = i * 256 + t;
      const int c   = lin >> 9;
      const int row = (lin >> 2) & 127;
      glds16(v_t + hb + (size_t)row * S_LEN + kv0 + c * 32 + col8, dst + (size_t)lin * 8);
    }
  };

  for (int ph = 0; ph < 2; ++ph) {
    const int qt     = ph ? pr : (15 - pr);
    const int qbase  = qt * 128;
    const int ntiles = 2 * qt + 2;
    const int wrow0  = qbase + w * 32;
    const int wrow_hi = wrow0 + 31;

    bf16x8 qf[2][4];
#pragma unroll
    for (int mi = 0; mi < 2; ++mi)
#pragma unroll
      for (int ks = 0; ks < 4; ++ks)
        qf[mi][ks] = *(const bf16x8*)(q_ws + hb + (size_t)(wrow0 + mi * 16 + l15) * HD + ks * 32 + quad * 8);

    f32x4 o_acc[2][8];
    float m_st[2][4], l_st[2][4];
#pragma unroll
    for (int mi = 0; mi < 2; ++mi) {
#pragma unroll
      for (int dt = 0; dt < 8; ++dt)
#pragma unroll
        for (int r = 0; r < 4; ++r) o_acc[mi][dt][r] = 0.f;
#pragma unroll
      for (int r = 0; r < 4; ++r) { m_st[mi][r] = -1e30f; l_st[mi][r] = 0.f; }
    }

    stageK(0, smK[0]);
    stageV(0, smV[0]);

    for (int tile = 0; tile < ntiles; ++tile) {
      const int cur = tile & 1;
      if (tile + 1 < ntiles) {
        const int kv1 = (tile + 1) * 64;
        stageK(kv1, smK[cur ^ 1]);
        stageV(kv1, smV[cur ^ 1]);
        asm volatile("s_waitcnt vmcnt(8)" ::: "memory");
      } else {
        asm volatile("s_waitcnt vmcnt(0)" ::: "memory");
      }
      __builtin_amdgcn_s_barrier();

      const int kv0 = tile * 64;
      if (kv0 <= wrow_hi) {
        f32x4 sc[2][4];
#pragma unroll
        for (int mi = 0; mi < 2; mi++)
#pragma unroll
          for (int ni = 0; ni < 4; ni++)
#pragma unroll
            for (int r = 0; r < 4; r++) sc[mi][ni][r] = 0.f;
        const bf16* kb = smK[cur];
#pragma unroll
        for (int ks = 0; ks < 4; ++ks) {
          bf16x8 kf[4];
#pragma unroll
          for (int ni = 0; ni < 4; ++ni)
            kf[ni] = *(const bf16x8*)(kb + (ks * 64 + ni * 16 + l15) * 32 + quad * 8);
#pragma unroll
          for (int mi = 0; mi < 2; ++mi)
#pragma unroll
            for (int ni = 0; ni < 4; ++ni)
              sc[mi][ni] = __builtin_amdgcn_mfma_f32_16x16x32_bf16(qf[mi][ks], kf[ni], sc[mi][ni], 0, 0, 0);
        }

#pragma unroll
        for (int mi = 0; mi < 2; ++mi) {
          const int mrow0 = wrow0 + mi * 16;
          const bool needmask = (kv0 + 63 > mrow0);
#pragma unroll
          for (int r = 0; r < 4; ++r) {
            const int qg = mrow0 + quad * 4 + r;
            float xs[4];
            float vmax = -1e30f;
            if (needmask) {
#pragma unroll
              for (int ni = 0; ni < 4; ++ni) {
                const int kg = kv0 + ni * 16 + l15;
                float xv = sc[mi][ni][r] * C;
                xv = (kg > qg) ? -1e30f : xv;
                xs[ni] = xv;
                vmax = fmaxf(vmax, xv);
              }
            } else {
#pragma unroll
              for (int ni = 0; ni < 4; ++ni) {
                const float xv = sc[mi][ni][r] * C;
                xs[ni] = xv;
                vmax = fmaxf(vmax, xv);
              }
            }
            float m_old = m_st[mi][r];
            if (!__all(vmax <= m_old + 8.f)) {
#pragma unroll
              for (int off = 1; off < 16; off <<= 1)
                vmax = fmaxf(vmax, __shfl_xor(vmax, off, 64));
              const float mnew  = fmaxf(m_old, vmax);
              const float alpha = __builtin_amdgcn_exp2f(m_old - mnew);
              l_st[mi][r] *= alpha;
#pragma unroll
              for (int dt = 0; dt < 8; ++dt) o_acc[mi][dt][r] *= alpha;
              m_st[mi][r] = mnew;
              m_old = mnew;
            }
            float ps = 0.f;
#pragma unroll
            for (int ni = 0; ni < 4; ++ni) {
              const float p = __builtin_amdgcn_exp2f(xs[ni] - m_old);
              ps += p;
              myP[(mi * 16 + quad * 4 + r) * 72 + ni * 16 + l15] = __float2bfloat16(p);
            }
            l_st[mi][r] += ps;
          }
        }

        const bf16* vb = smV[cur];
#pragma unroll
        for (int ks2 = 0; ks2 < 2; ++ks2) {
          bf16x8 pa[2];
#pragma unroll
          for (int mi = 0; mi < 2; ++mi)
            pa[mi] = *(const bf16x8*)(myP + (mi * 16 + l15) * 72 + ks2 * 32 + quad * 8);
#pragma unroll
          for (int dt = 0; dt < 8; ++dt) {
            const bf16x8 vf = *(const bf16x8*)(vb + (ks2 * 128 + dt * 16 + l15) * 32 + quad * 8);
#pragma unroll
            for (int mi = 0; mi < 2; ++mi)
              o_acc[mi][dt] = __builtin_amdgcn_mfma_f32_16x16x32_bf16(pa[mi], vf, o_acc[mi][dt], 0, 0, 0);
          }
        }
      }
      __builtin_amdgcn_s_barrier();
    }

#pragma unroll
    for (int mi = 0; mi < 2; ++mi) {
#pragma unroll
      for (int r = 0; r < 4; ++r) {
        float l = l_st[mi][r];
#pragma unroll
        for (int off = 1; off < 16; off <<= 1) l += __shfl_xor(l, off, 64);
        const float rl = 1.f / l;
        const int sg = qbase + w * 32 + mi * 16 + quad * 4 + r;
        const size_t rowoff = hb + (size_t)sg * HD;
#pragma unroll
        for (int dt = 0; dt < 8; ++dt)
          attn_out[rowoff + dt * 16 + l15] = __float2bfloat16(o_acc[mi][dt][r] * rl);
      }
    }
  }
}

// ---------------------------------------------------------------------------
// Kernel 3: out = attn @ w_out^T + b_out, attn stored [b,h,s,d]
// (logical A[m = b*2048+s][k = h*128+d]). OUTPUT FLOAT32. Grid (8,32).
// Same triple-buffered structure as gemm_qkv_k.
// ---------------------------------------------------------------------------
__global__ __launch_bounds__(512, 1) void gemm_out_k(
    const bf16* __restrict__ attn, const bf16* __restrict__ wo,
    const float* __restrict__ bias, float* __restrict__ out)
{
  __shared__ alignas(16) bf16 sA[3][128 * 64];
  __shared__ alignas(16) bf16 sB[3][256 * 64];

  const int t    = threadIdx.x;
  const int lane = t & 63, quad = lane >> 4, l15 = lane & 15;
  const int w    = t >> 6, wm = w >> 2, wn = w & 3;

  const int n0 = blockIdx.x * 256;
  const int m0 = blockIdx.y * 128;

  auto stA = [&](int k0, int buf) {
    const int h  = k0 >> 7;
    const int d0 = k0 & 127;
#pragma unroll
    for (int i = 0; i < 2; ++i) {
      const int lin = i * 512 + t;
      const int row = lin >> 3;
      const int cb  = ((lin & 7) * 16) ^ ((row & 7) << 4);
      const int m   = m0 + row;
      const int b   = m >> 11;
      const int s   = m & 2047;
      glds16(attn + ((size_t)(b * NH + h) * S_LEN + s) * HD + d0 + (cb >> 1),
             sA[buf] + (size_t)lin * 8);
    }
  };
  auto stB = [&](int k0, int buf) {
#pragma unroll
    for (int i = 0; i < 4; ++i) {
      const int lin = i * 512 + t;
      const int row = lin >> 3;
      const int cb  = ((lin & 7) * 16) ^ ((row & 7) << 4);
      glds16(wo + (size_t)(n0 + row) * EMB + k0 + (cb >> 1),
             sB[buf] + (size_t)lin * 8);
    }
  };

  f32x4 acc[4][4];
#pragma unroll
  for (int mi = 0; mi < 4; ++mi)
#pragma unroll
    for (int ni = 0; ni < 4; ++ni)
#pragma unroll
      for (int r = 0; r < 4; ++r) acc[mi][ni][r] = 0.f;

  stA(0, 0); stB(0, 0);
  stA(64, 1); stB(64, 1);

  int cur = 0;
  for (int kt = 0; kt < 32; ++kt) {
    if (kt < 31) asm volatile("s_waitcnt vmcnt(6)" ::: "memory");
    else         asm volatile("s_waitcnt vmcnt(0)" ::: "memory");
    __builtin_amdgcn_s_barrier();

    if (kt + 2 < 32) {
      int pf = cur - 1; if (pf < 0) pf += 3;
      stA((kt + 2) * 64, pf);
      stB((kt + 2) * 64, pf);
    }

    const bf16* aB = sA[cur];
    const bf16* bB = sB[cur];
    bf16x8 af[4][2], bfr[4][2];
#pragma unroll
    for (int mi = 0; mi < 4; ++mi)
#pragma unroll
      for (int kk = 0; kk < 2; ++kk) {
        const int ar = wm * 64 + mi * 16 + l15;
        const int c  = (kk * 64 + quad * 16) ^ ((ar & 7) << 4);
        af[mi][kk] = *(const bf16x8*)(aB + ar * 64 + (c >> 1));
      }
#pragma unroll
    for (int ni = 0; ni < 4; ++ni)
#pragma unroll
      for (int kk = 0; kk < 2; ++kk) {
        const int br = wn * 64 + ni * 16 + l15;
        const int c  = (kk * 64 + quad * 16) ^ ((br & 7) << 4);
        bfr[ni][kk] = *(const bf16x8*)(bB + br * 64 + (c >> 1));
      }
    __builtin_amdgcn_s_setprio(1);
#pragma unroll
    for (int mi = 0; mi < 4; ++mi)
#pragma unroll
      for (int ni = 0; ni < 4; ++ni)
#pragma unroll
        for (int kk = 0; kk < 2; ++kk)
          acc[mi][ni] = __builtin_amdgcn_mfma_f32_16x16x32_bf16(af[mi][kk], bfr[ni][kk], acc[mi][ni], 0, 0, 0);
    __builtin_amdgcn_s_setprio(0);

    cur = (cur == 2) ? 0 : cur + 1;
  }

#pragma unroll
  for (int mi = 0; mi < 4; ++mi) {
#pragma unroll
    for (int ni = 0; ni < 4; ++ni) {
      const int n_g = n0 + wn * 64 + ni * 16 + l15;
      const float bv = bias[n_g];
#pragma unroll
      for (int r = 0; r < 4; ++r) {
        const int m_g = m0 + wm * 64 + mi * 16 + quad * 4 + r;
        out[(size_t)m_g * EMB + n_g] = acc[mi][ni][r] + bv;   // f32 store
      }
    }
  }
}

// ---------------------------------------------------------------------------
// Workspace layout (96 MiB):
//   [ 0,16)  MiB: xb  bf16 (x converted) -> attn output [b,h,s,d] after QKV
//   [16,40)  MiB: wqb bf16 (w_qkv converted)
//   [40,48)  MiB: wob bf16 (w_out converted)
//   [48,64)  MiB: q [b,h,s,d]
//   [64,80)  MiB: k [b,h,s,d]
//   [80,96)  MiB: v_t [b,h,d,s]
// ---------------------------------------------------------------------------
extern "C" void kernel_launch(void* const* d_in, const int* in_sizes, int n_in,
                              void* d_out, int out_size, void* d_ws, size_t ws_size,
                              hipStream_t stream)
{
  const float* x_f     = (const float*)d_in[0];
  // d_in[1] = attn_mask (causal triu) — known analytically, ignored.
  const float* w_qkv_f = (const float*)d_in[2];
  const float* b_qkv   = (const float*)d_in[3];
  const float* w_out_f = (const float*)d_in[4];
  const float* b_out   = (const float*)d_in[5];
  float* out = (float*)d_out;   // reference output dtype is float32

  char* ws = (char*)d_ws;
  const size_t MB = 1024 * 1024;
  bf16* xb   = (bf16*)(ws);
  bf16* wqb  = (bf16*)(ws + 16 * MB);
  bf16* wob  = (bf16*)(ws + 40 * MB);
  bf16* q_ws = (bf16*)(ws + 48 * MB);
  bf16* k_ws = (bf16*)(ws + 64 * MB);
  bf16* v_t  = (bf16*)(ws + 80 * MB);
  bf16* attn = xb;   // xb dead after gemm_qkv_k; distinct from q_ws (no alias)

  cvt_f32_bf16_k<<<dim3(8192), 256, 0, stream>>>(x_f, xb);
  cvt_f32_bf16_k<<<dim3(12288), 256, 0, stream>>>(w_qkv_f, wqb);
  cvt_f32_bf16_k<<<dim3(4096), 256, 0, stream>>>(w_out_f, wob);

  gemm_qkv_k<<<dim3(24, 32), 512, 0, stream>>>(xb, wqb, b_qkv, q_ws, k_ws, v_t);
  attn_k<<<dim3(256), 256, 0, stream>>>(q_ws, k_ws, v_t, attn);
  gemm_out_k<<<dim3(8, 32), 512, 0, stream>>>(attn, wob, b_out, out);
}